// Round 16
// baseline (381.890 us; speedup 1.0000x reference)
//
#include <hip/hip_runtime.h>

typedef unsigned short u16;
typedef __attribute__((ext_vector_type(4))) int i4;
typedef __attribute__((ext_vector_type(4))) unsigned u4;
typedef __attribute__((ext_vector_type(4))) unsigned short us4;
typedef __attribute__((ext_vector_type(8))) short short8;
typedef __attribute__((ext_vector_type(4))) float f4;

#define D_MODEL 1024
#define ROWS 4096      // B*L and MEM_SIZE
#define NHEAD 8
#define DH 128
#define TOPK 409
#define NUPD 1636      // B*TOPK
#define NBATCH 4
#define MAXC 64        // max chained updates tracked per memory row
#define ATTNROWS 32768 // B*H*L rows of (head-sliced) attention output
// 1/sqrt(128) * log2(e): q pre-scaled so attention softmax works in exp2 domain
#define QSCALE 0.1275174038f

__device__ __forceinline__ u16 f2bf(float f) {
  unsigned u = __builtin_bit_cast(unsigned, f);
  u += 0x7fffu + ((u >> 16) & 1u);
  return (u16)(u >> 16);
}
__device__ __forceinline__ float bf2f(u16 b) {
  unsigned u = ((unsigned)b) << 16;
  return __builtin_bit_cast(float, u);
}
__device__ __forceinline__ float ex2(float x) {  // native v_exp_f32 (2^x)
  return __builtin_amdgcn_exp2f(x);
}
__device__ __forceinline__ float gelu_f(float v) {
  return 0.5f * v * (1.0f + erff(v * 0.70710678118654752f));
}
__device__ __forceinline__ void gload16(const void* g, void* l) {
  __builtin_amdgcn_global_load_lds((const __attribute__((address_space(1))) void*)g,
                                   (__attribute__((address_space(3))) void*)l, 16, 0, 0);
}

// ---------------- paired convert f32 -> bf16 (vectorized) ----------------
__global__ __launch_bounds__(256) void conv2_kernel(const float* __restrict__ in0,
                                                    u16* __restrict__ out0,
                                                    const float* __restrict__ in1,
                                                    u16* __restrict__ out1, int nb) {
  int bid = blockIdx.x;
  const float* in = (bid < nb) ? in0 : in1;
  u16* out = (bid < nb) ? out0 : out1;
  int i = (bid < nb ? bid : bid - nb) * 256 + threadIdx.x;
  f4 v = ((const f4*)in)[i];
  us4 o;
  o.x = f2bf(v.x); o.y = f2bf(v.y); o.z = f2bf(v.z); o.w = f2bf(v.w);
  ((us4*)out)[i] = o;
}

// ---------------- fused weight transpose: 8x w[1024][1024] f32 -> wt[N][K] bf16 ----------------
__global__ __launch_bounds__(256) void wtrans8_kernel(const float* s0, const float* s1,
                                                      const float* s2, const float* s3,
                                                      const float* s4, const float* s5,
                                                      const float* s6, const float* s7,
                                                      u16* __restrict__ dst) {
  const float* srcs[8] = {s0, s1, s2, s3, s4, s5, s6, s7};
  const float* w = srcs[blockIdx.z];
  u16* wt = dst + (size_t)blockIdx.z * (1024 * 1024);
  __shared__ float t[32][33];
  int tx = threadIdx.x & 31, ty = threadIdx.x >> 5;
  int k0 = blockIdx.y * 32, n0 = blockIdx.x * 32;
  for (int r = 0; r < 4; ++r)
    t[ty + r * 8][tx] = w[(size_t)(k0 + ty + r * 8) * 1024 + n0 + tx];
  __syncthreads();
  for (int r = 0; r < 4; ++r)
    wt[(size_t)(n0 + ty + r * 8) * 1024 + k0 + tx] = f2bf(t[tx][ty + r * 8]);
}

// ---------------- bias prep, stage B: reduce + add base bias ----------------
__global__ __launch_bounds__(256) void bias_partB(const float* __restrict__ pbuf,
                                                  const float* __restrict__ bq,
                                                  const float* __restrict__ db1,
                                                  float* __restrict__ bqp,
                                                  float* __restrict__ bodp) {
  int id = blockIdx.x;  // 8 = which*4 + nc
  int which = id >> 2;
  int n = (id & 3) * 256 + threadIdx.x;
  float s = 0.0f;
  for (int kb = 0; kb < 8; ++kb) s += pbuf[(size_t)(which * 8 + kb) * 1024 + n];
  float* out = which ? bodp : bqp;
  const float* badd = which ? db1 : bq;
  out[n] = s + badd[n];
}

// ---------------- shared GEMM core: acc[4][2] += A[m0:m0+128] x BT[n0:n0+64]^T ----------
__device__ __forceinline__ void gemm_core(const u16* __restrict__ A,
                                          const u16* __restrict__ BT,
                                          char* al, char* bl, int m0, int n0,
                                          f4 acc[4][2]) {
  const int K = 1024;
  const int tid = threadIdx.x;
  const int lane = tid & 63;
  const int g = lane >> 4, qi = lane & 15;
  const int wid = tid >> 6;
  const int wr = wid >> 1, wc = wid & 1;
  const int a0r = tid >> 2, a0b = (tid & 3) ^ ((a0r >> 1) & 3);
  const int c1 = tid + 256;
  const int a1r = c1 >> 2, a1b = (c1 & 3) ^ ((a1r >> 1) & 3);
  const int b0r = tid >> 2, b0b = (tid & 3) ^ ((b0r >> 1) & 3);

#define STAGE(buf, kt)                                                                   \
  {                                                                                      \
    const int k0_ = (kt) * 32;                                                           \
    gload16(A + (size_t)(m0 + a0r) * K + k0_ + a0b * 8, al + (buf) * 8192 + tid * 16);   \
    gload16(A + (size_t)(m0 + a1r) * K + k0_ + a1b * 8, al + (buf) * 8192 + c1 * 16);    \
    gload16(BT + (size_t)(n0 + b0r) * K + k0_ + b0b * 8, bl + (buf) * 4096 + tid * 16);  \
  }

  STAGE(0, 0);
  __syncthreads();
  int cur = 0;
  for (int kt = 0; kt < 32; ++kt) {
    if (kt + 1 < 32) STAGE(cur ^ 1, kt + 1);
    short8 af[4], bfr[2];
    for (int i = 0; i < 4; ++i) {
      int r = wr * 64 + i * 16 + qi;
      af[i] = *(const short8*)(al + cur * 8192 + r * 64 + ((g ^ ((r >> 1) & 3))) * 16);
    }
    for (int sn = 0; sn < 2; ++sn) {
      int r = wc * 32 + sn * 16 + qi;
      bfr[sn] = *(const short8*)(bl + cur * 4096 + r * 64 + ((g ^ ((r >> 1) & 3))) * 16);
    }
    for (int i = 0; i < 4; ++i)
      for (int sn = 0; sn < 2; ++sn)
        acc[i][sn] = __builtin_amdgcn_mfma_f32_16x16x32_bf16(af[i], bfr[sn], acc[i][sn], 0, 0, 0);
    __syncthreads();
    cur ^= 1;
  }
#undef STAGE
}

// ---------------- MEGA dispatch: kv(1024) | e1(512) | sq(256) | biasA(64) | imp(512) ----
__global__ __launch_bounds__(256) void mega_kernel(
    const u16* __restrict__ Akv, const u16* __restrict__ BTkv,
    const float* __restrict__ bk, const float* __restrict__ bv,
    u16* __restrict__ Ck, u16* __restrict__ CvT,
    const u16* __restrict__ Ae, const u16* __restrict__ BTe,
    const float* __restrict__ be, u16* __restrict__ Ce,
    const u16* __restrict__ A0, const u16* __restrict__ B0, u16* __restrict__ C0,
    const u16* __restrict__ A1, const u16* __restrict__ B1, u16* __restrict__ C1,
    const float* __restrict__ b2, const float* __restrict__ wqf,
    const float* __restrict__ bo, const float* __restrict__ dw1,
    float* __restrict__ pbuf,
    const float* __restrict__ x, const float* __restrict__ iw1,
    const float* __restrict__ ib1, const float* __restrict__ iw2,
    const float* __restrict__ ib2, float* __restrict__ imp) {
  __shared__ __align__(16) char pool[32768];
  char* al = pool;
  char* bl = pool + 2 * 128 * 64;
  const int gid = blockIdx.x;
  const int tid = threadIdx.x;
  const int lane = tid & 63, wid = tid >> 6;
  const int g = lane >> 4, qi = lane & 15;
  const int wr = wid >> 1, wc = wid & 1;

  if (gid < 1024) {  // ---- merged K/V projection (XCD-pinned) ----
    const int xcd = gid & 7, j = gid >> 3;
    const int m0 = ((j & 3) * 8 + xcd) * 128;
    const int n0 = (j >> 2) * 64;  // 0..2047
    f4 acc[4][2] = {};
    gemm_core(Akv, BTkv, al, bl, m0, n0, acc);
    if (n0 < 1024) {  // K path
      for (int i = 0; i < 4; ++i) {
        int row = m0 + wr * 64 + i * 16 + g * 4;
        for (int sn = 0; sn < 2; ++sn) {
          int col = n0 + wc * 32 + sn * 16 + qi;
          float bvv = bk[col];
          for (int jj = 0; jj < 4; ++jj)
            Ck[(size_t)(row + jj) * 1024 + col] = f2bf(acc[i][sn][jj] + bvv);
        }
      }
    } else {  // V path: transposed store via padded LDS
      u16(*t)[132] = (u16(*)[132])pool;
      __syncthreads();
      for (int i = 0; i < 4; ++i)
        for (int sn = 0; sn < 2; ++sn) {
          int nl = wc * 32 + sn * 16 + qi;
          float bvv = bv[n0 - 1024 + nl];
          for (int jj = 0; jj < 4; ++jj)
            t[nl][wr * 64 + i * 16 + g * 4 + jj] = f2bf(acc[i][sn][jj] + bvv);
        }
      __syncthreads();
      int r = tid >> 2, cg = tid & 3;
      for (int v = 0; v < 4; ++v) {
        us4 val = *(const us4*)&t[r][cg * 32 + v * 8];
        *(us4*)&CvT[(size_t)(n0 - 1024 + r) * 4096 + m0 + cg * 32 + v * 8] = val;
      }
    }
  } else if (gid < 1536) {  // ---- encoder-1 GEMM + GELU (XCD-pinned) ----
    const int id = gid - 1024;
    const int xcd = id & 7, j = id >> 3;
    const int m0 = ((j & 3) * 8 + xcd) * 128;
    const int n0 = (j >> 2) * 64;
    f4 acc[4][2] = {};
    gemm_core(Ae, BTe, al, bl, m0, n0, acc);
    for (int i = 0; i < 4; ++i) {
      int row = m0 + wr * 64 + i * 16 + g * 4;
      for (int sn = 0; sn < 2; ++sn) {
        int col = n0 + wc * 32 + sn * 16 + qi;
        float bv = be[col];
        for (int jj = 0; jj < 4; ++jj)
          Ce[(size_t)(row + jj) * 1024 + col] = f2bf(gelu_f(acc[i][sn][jj] + bv));
      }
    }
  } else if (gid < 1792) {  // ---- dual weight-product GEMM (no bias) ----
    const int id = gid - 1536;
    const int which = id >> 7, j = id & 127;
    const u16* A = which ? A1 : A0;
    const u16* BT = which ? B1 : B0;
    u16* C = which ? C1 : C0;
    const int m0 = (j >> 4) * 128, n0 = (j & 15) * 64;
    f4 acc[4][2] = {};
    gemm_core(A, BT, al, bl, m0, n0, acc);
    for (int i = 0; i < 4; ++i) {
      int row = m0 + wr * 64 + i * 16 + g * 4;
      for (int sn = 0; sn < 2; ++sn) {
        int col = n0 + wc * 32 + sn * 16 + qi;
        for (int jj = 0; jj < 4; ++jj)
          C[(size_t)(row + jj) * 1024 + col] = f2bf(acc[i][sn][jj]);
      }
    }
  } else if (gid < 1856) {  // ---- bias partials ----
    const int lid = gid - 1792;
    const int which = lid >> 5;
    const int kb = (lid >> 2) & 7;
    const int n = (lid & 3) * 256 + tid;
    const float* bvec = which ? bo : b2;
    const float* W = which ? dw1 : wqf;
    float s = 0.0f;
    for (int k = kb * 128; k < kb * 128 + 128; ++k) s += bvec[k] * W[(size_t)k * 1024 + n];
    pbuf[(size_t)(which * 8 + kb) * 1024 + n] = s;
  } else {  // ---- importance scorer (8 rows/block, wave-shuffle reduce) ----
    const int lid = gid - 1856;
    float* xs = (float*)pool;  // [8][1024]
    size_t base = (size_t)lid * 8192;
    for (int i = 0; i < 32; ++i) xs[tid + i * 256] = x[base + tid + i * 256];
    __syncthreads();
    int r0 = wid * 2, r1 = wid * 2 + 1;
    float a0 = 0.0f, a1 = 0.0f;
    for (int k = 0; k < 1024; ++k) {
      float wv = iw1[k * 64 + lane];
      a0 += xs[r0 * 1024 + k] * wv;
      a1 += xs[r1 * 1024 + k] * wv;
    }
    float h0 = gelu_f(a0 + ib1[lane]) * iw2[lane];
    float h1 = gelu_f(a1 + ib1[lane]) * iw2[lane];
    for (int d = 1; d < 64; d <<= 1) {
      h0 += __shfl_xor(h0, d, 64);
      h1 += __shfl_xor(h1, d, 64);
    }
    if (lane == 0) {
      imp[lid * 8 + r0] = 1.0f / (1.0f + expf(-(h0 + ib2[0])));
      imp[lid * 8 + r1] = 1.0f / (1.0f + expf(-(h1 + ib2[0])));
    }
  }
}

// ---------------- bf16 GEMM: C[4096][1024] = A * BT^T + bias ----------------
// EPI: 0 = bf16, 1 = GELU+bf16, 2 = f32, 4 = bf16 * QSCALE (exp2-domain q)
template <int EPI>
__global__ __launch_bounds__(256) void gemm_bt(const u16* __restrict__ A,
                                               const u16* __restrict__ BT,
                                               const float* __restrict__ bias,
                                               void* __restrict__ C) {
  __shared__ __align__(16) char al[2 * 128 * 64];
  __shared__ __align__(16) char bl[2 * 64 * 64];
  const int N = 1024;
  const int id = blockIdx.x;
  const int xcd = id & 7, j = id >> 3;
  const int m0 = ((j & 3) * 8 + xcd) * 128;
  const int n0 = (j >> 2) * 64;
  const int tid = threadIdx.x;
  const int lane = tid & 63, wid = tid >> 6;
  const int g = lane >> 4, qi = lane & 15;
  const int wr = wid >> 1, wc = wid & 1;
  f4 acc[4][2] = {};
  gemm_core(A, BT, al, bl, m0, n0, acc);
  for (int i = 0; i < 4; ++i) {
    int row = m0 + wr * 64 + i * 16 + g * 4;
    for (int sn = 0; sn < 2; ++sn) {
      int col = n0 + wc * 32 + sn * 16 + qi;
      float bv = bias[col];
      for (int jj = 0; jj < 4; ++jj) {
        float v = acc[i][sn][jj] + bv;
        if constexpr (EPI == 1) v = gelu_f(v);
        if constexpr (EPI == 4) v = v * QSCALE;
        if constexpr (EPI == 2)
          ((float*)C)[(size_t)(row + jj) * N + col] = v;
        else
          ((u16*)C)[(size_t)(row + jj) * N + col] = f2bf(v);
      }
    }
  }
}

// ---------------- flash cross-attention, split-K, dual-Q fragments ----------------
// 8 waves x 32 q-rows each (two 16-q halves share every K/V LDS fragment read).
// LP=2: 4-way split -> grid 512 = 2 blocks/CU (4 waves/SIMD with VGPR~100).
template <int LP>
__global__ __launch_bounds__(512) void attn_kernel(const u16* __restrict__ q,
                                                   const u16* __restrict__ kp,
                                                   const u16* __restrict__ vT,
                                                   u16* __restrict__ cp0, u16* __restrict__ cp1,
                                                   u16* __restrict__ cp2, u16* __restrict__ cp3,
                                                   float* __restrict__ ml) {
  constexpr int MR = 4096 >> LP;  // memory rows per part
  constexpr int NT = MR / 64;
  __shared__ __align__(16) char kl[64 * 256];   // K tile [64][128] bf16, XOR-swizzled
  __shared__ __align__(16) char vl[128 * 128];  // V^T tile [128][64] bf16, XOR-swizzled
  const int id = blockIdx.x;
  const int h = id & 7;
  const int rest = id >> 3;
  const int part = rest & ((1 << LP) - 1);
  const int qsec = (rest >> LP) & 3;
  const int b = rest >> (2 + LP);
  const int tid = threadIdx.x;
  const int lane = tid & 63, wid = tid >> 6;
  const int g = lane >> 4, qi = lane & 15;
  const int qrow0 = b * 1024 + qsec * 256 + wid * 32 + qi;  // half 0
  const int qrow1 = qrow0 + 16;                             // half 1
  u16* ctp = (part == 0) ? cp0 : (part == 1) ? cp1 : (part == 2) ? cp2 : cp3;

  short8 qf0[4], qf1[4];
  for (int kk = 0; kk < 4; ++kk) {
    qf0[kk] = *(const short8*)(q + (size_t)qrow0 * 1024 + h * 128 + kk * 32 + g * 8);
    qf1[kk] = *(const short8*)(q + (size_t)qrow1 * 1024 + h * 128 + kk * 32 + g * 8);
  }

  // staging geometry (2 K-blocks + 2 V-blocks per thread, 512 threads)
  const int kc1 = tid + 512;
  const int kr0 = tid >> 4, kb0 = tid & 15, kr1 = kc1 >> 4, kb1 = kc1 & 15;
  const int vr0 = tid >> 3, vb0 = tid & 7, vr1 = kc1 >> 3, vb1 = kc1 & 7;
  const int kd0 = kr0 * 256 + (kb0 ^ (kr0 & 7)) * 16;
  const int kd1 = kr1 * 256 + (kb1 ^ (kr1 & 7)) * 16;
  const int vd0 = vr0 * 128 + (vb0 ^ (vr0 & 7)) * 16;
  const int vd1 = vr1 * 128 + (vb1 ^ (vr1 & 7)) * 16;
  const int mbase = part * MR;
  const u16* kg0 = kp + (size_t)(mbase + kr0) * 1024 + h * 128 + kb0 * 8;
  const u16* kg1 = kp + (size_t)(mbase + kr1) * 1024 + h * 128 + kb1 * 8;
  const u16* vg0 = vT + (size_t)(h * 128 + vr0) * 4096 + mbase + vb0 * 8;
  const u16* vg1 = vT + (size_t)(h * 128 + vr1) * 4096 + mbase + vb1 * 8;

  i4 kreg0, kreg1, vreg0, vreg1;
#define LOADREGS()                              \
  {                                             \
    kreg0 = *(const i4*)kg0; kg0 += 64 * 1024;  \
    kreg1 = *(const i4*)kg1; kg1 += 64 * 1024;  \
    vreg0 = *(const i4*)vg0; vg0 += 64;         \
    vreg1 = *(const i4*)vg1; vg1 += 64;         \
  }

  f4 ct0[8] = {}, ct1[8] = {};
  float mrun0 = -1e30f, lsum0 = 0.0f, mrun1 = -1e30f, lsum1 = 0.0f;

  LOADREGS();
  for (int mt = 0; mt < NT; ++mt) {
    __syncthreads();
    *(i4*)(kl + kd0) = kreg0; *(i4*)(kl + kd1) = kreg1;
    *(i4*)(vl + vd0) = vreg0; *(i4*)(vl + vd1) = vreg1;
    __syncthreads();
    if (mt + 1 < NT) LOADREGS();  // in flight during compute

    // S^T = K_tile x Q^T for both q-halves; each K fragment feeds 2 MFMAs
    f4 st0[4] = {}, st1[4] = {};
    for (int s = 0; s < 4; ++s) {
      int n = s * 16 + qi;
      const char* krow = kl + n * 256;
      int sw = n & 7;
      for (int kk = 0; kk < 4; ++kk) {
        short8 a = *(const short8*)(krow + ((kk * 4 + g) ^ sw) * 16);
        st0[s] = __builtin_amdgcn_mfma_f32_16x16x32_bf16(a, qf0[kk], st0[s], 0, 0, 0);
        st1[s] = __builtin_amdgcn_mfma_f32_16x16x32_bf16(a, qf1[kk], st1[s], 0, 0, 0);
      }
    }

    short8 pfa0, pfb0, pfa1, pfb1;  // PV B-fragments for halves 0/1, n-chunks a/b
#define SOFTMAX_PACK(ST, MRUN, LSUM, CT, PFA, PFB)                                        \
    {                                                                                     \
      float sv[16];                                                                       \
      float tm = -1e30f;                                                                  \
      for (int s = 0; s < 4; ++s)                                                         \
        for (int jj = 0; jj < 4; ++jj) {                                                  \
          sv[s * 4 + jj] = ST[s][jj];                                                     \
          tm = fmaxf(tm, ST[s][jj]);                                                      \
        }                                                                                 \
      tm = fmaxf(tm, __shfl_xor(tm, 16, 64));                                             \
      tm = fmaxf(tm, __shfl_xor(tm, 32, 64));                                             \
      if (!__all(tm <= MRUN + 8.0f)) {                                                    \
        float mnew = fmaxf(MRUN, tm);                                                     \
        float r = ex2(MRUN - mnew);                                                       \
        LSUM *= r;                                                                        \
        for (int i = 0; i < 8; ++i) CT[i] = CT[i] * r;                                    \
        MRUN = mnew;                                                                      \
      }                                                                                   \
      float psum = 0.0f;                                                                  \
      for (int i = 0; i < 16; ++i) {                                                      \
        float p = ex2(sv[i] - MRUN);                                                      \
        sv[i] = p;                                                                        \
        psum += p;                                                                        \
      }                                                                                   \
      psum += __shfl_xor(psum, 16, 64);                                                   \
      psum += __shfl_xor(psum, 32, 64);                                                   \
      LSUM += psum;                                                                       \
      unsigned pk0[4], pk1[4];                                                            \
      for (int s = 0; s < 4; ++s) {                                                       \
        pk0[s] = (unsigned)f2bf(sv[s * 4 + 0]) | ((unsigned)f2bf(sv[s * 4 + 1]) << 16);   \
        pk1[s] = (unsigned)f2bf(sv[s * 4 + 2]) | ((unsigned)f2bf(sv[s * 4 + 3]) << 16);   \
      }                                                                                   \
      const int src1 = qi + ((g & 1) << 5);                                               \
      const int src2 = src1 + 16;                                                         \
      const bool hi = (g & 2) != 0;                                                       \
      {                                                                                   \
        unsigned a0 = __shfl(pk0[0], src1, 64), b0 = __shfl(pk0[1], src1, 64);            \
        unsigned a1 = __shfl(pk1[0], src1, 64), b1 = __shfl(pk1[1], src1, 64);            \
        unsigned a2 = __shfl(pk0[0], src2, 64), b2 = __shfl(pk0[1], src2, 64);            \
        unsigned a3 = __shfl(pk1[0], src2, 64), b3 = __shfl(pk1[1], src2, 64);            \
        u4 bw;                                                                            \
        bw.x = hi ? b0 : a0; bw.y = hi ? b1 : a1; bw.z = hi ? b2 : a2; bw.w = hi ? b3 : a3;\
        PFA = __builtin_bit_cast(short8, bw);                                             \
      }                                                                                   \
      {                                                                                   \
        unsigned a0 = __shfl(pk0[2], src1, 64), b0 = __shfl(pk0[3], src1, 64);            \
        unsigned a1 = __shfl(pk1[2], src1, 64), b1 = __shfl(pk1[3], src1, 64);            \
        unsigned a2 = __shfl(pk0[2], src2, 64), b2 = __shfl(pk0[3], src2, 64);            \
        unsigned a3 = __shfl(pk1[2], src2, 64), b3 = __shfl(pk1[3], src2, 64);            \
        u4 bw;                                                                            \
        bw.x = hi ? b0 : a0; bw.y = hi ? b1 : a1; bw.z = hi ? b2 : a2; bw.w = hi ? b3 : a3;\
        PFB = __builtin_bit_cast(short8, bw);                                             \
      }                                                                                   \
    }
    SOFTMAX_PACK(st0, mrun0, lsum0, ct0, pfa0, pfb0);
    SOFTMAX_PACK(st1, mrun1, lsum1, ct1, pfa1, pfb1);
#undef SOFTMAX_PACK

    // PV: each V fragment feeds 2 MFMAs (one per q-half)
    for (int d = 0; d < 8; ++d) {
      int dr = d * 16 + qi;
      const char* vrow = vl + dr * 128;
      int swv = dr & 7;
      short8 a0 = *(const short8*)(vrow + ((0 + g) ^ swv) * 16);
      ct0[d] = __builtin_amdgcn_mfma_f32_16x16x32_bf16(a0, pfa0, ct0[d], 0, 0, 0);
      ct1[d] = __builtin_amdgcn_mfma_f32_16x16x32_bf16(a0, pfa1, ct1[d], 0, 0, 0);
      short8 a1 = *(const short8*)(vrow + ((4 + g) ^ swv) * 16);
      ct0[d] = __builtin_amdgcn_mfma_f32_16x16x32_bf16(a1, pfb0, ct0[d], 0, 0, 0);
      ct1[d] = __builtin_amdgcn_mfma_f32_16x16x32_bf16(a1, pfb1, ct1[d], 0, 0, 0);
    }
  }
#undef LOADREGS

  const int obase = ((b * 8 + h) << 10) + qsec * 256 + wid * 32 + qi;
  if (g == 0) {
    ml[(size_t)(part * ATTNROWS + obase) * 2 + 0] = mrun0;
    ml[(size_t)(part * ATTNROWS + obase) * 2 + 1] = lsum0;
    ml[(size_t)(part * ATTNROWS + obase + 16) * 2 + 0] = mrun1;
    ml[(size_t)(part * ATTNROWS + obase + 16) * 2 + 1] = lsum1;
  }
  for (int d = 0; d < 8; ++d) {
    us4 o0, o1;
    o0.x = f2bf(ct0[d][0]); o0.y = f2bf(ct0[d][1]);
    o0.z = f2bf(ct0[d][2]); o0.w = f2bf(ct0[d][3]);
    o1.x = f2bf(ct1[d][0]); o1.y = f2bf(ct1[d][1]);
    o1.z = f2bf(ct1[d][2]); o1.w = f2bf(ct1[d][3]);
    *(us4*)(ctp + (size_t)obase * 128 + d * 16 + g * 4) = o0;
    *(us4*)(ctp + (size_t)(obase + 16) * 128 + d * 16 + g * 4) = o1;
  }
}

// ---------------- combine 4 split-K partials -> ctx [4096][1024] bf16 (exp2 domain) -----
__global__ __launch_bounds__(256) void combine4_kernel(const u16* __restrict__ cp0,
                                                       const u16* __restrict__ cp1,
                                                       const u16* __restrict__ cp2,
                                                       const u16* __restrict__ cp3,
                                                       const float* __restrict__ ml,
                                                       u16* __restrict__ ctx) {
  int tid = threadIdx.x;
  int row = blockIdx.x * 16 + (tid >> 4);
  int dp = (tid & 15) * 8;
  float m0 = ml[(size_t)row * 2], l0 = ml[(size_t)row * 2 + 1];
  float m1 = ml[((size_t)ATTNROWS + row) * 2], l1 = ml[((size_t)ATTNROWS + row) * 2 + 1];
  float m2 = ml[((size_t)2 * ATTNROWS + row) * 2], l2 = ml[((size_t)2 * ATTNROWS + row) * 2 + 1];
  float m3 = ml[((size_t)3 * ATTNROWS + row) * 2], l3 = ml[((size_t)3 * ATTNROWS + row) * 2 + 1];
  float m = fmaxf(fmaxf(m0, m1), fmaxf(m2, m3));
  float s0 = ex2(m0 - m), s1 = ex2(m1 - m), s2 = ex2(m2 - m), s3 = ex2(m3 - m);
  float inv = 1.0f / (l0 * s0 + l1 * s1 + l2 * s2 + l3 * s3);
  short8 c0 = *(const short8*)(cp0 + (size_t)row * 128 + dp);
  short8 c1 = *(const short8*)(cp1 + (size_t)row * 128 + dp);
  short8 c2 = *(const short8*)(cp2 + (size_t)row * 128 + dp);
  short8 c3 = *(const short8*)(cp3 + (size_t)row * 128 + dp);
  us4 o[2];
  for (int i = 0; i < 8; ++i) {
    float f = (bf2f((u16)c0[i]) * s0 + bf2f((u16)c1[i]) * s1 + bf2f((u16)c2[i]) * s2 +
               bf2f((u16)c3[i]) * s3) * inv;
    ((u16*)o)[i] = f2bf(f);
  }
  int bb = row >> 13, hh = (row >> 10) & 7, qr = row & 1023;
  *(short8*)(ctx + (size_t)((bb << 10) + qr) * 1024 + hh * 128 + dp) =
      __builtin_bit_cast(short8, o);
}

// ---------------- residual + LayerNorm (also zeroes EMA cnt) ----------------
__global__ __launch_bounds__(256) void ln_kernel(const float* __restrict__ x,
                                                 const float* __restrict__ dec,
                                                 const float* __restrict__ gw,
                                                 const float* __restrict__ bw,
                                                 float* __restrict__ out,
                                                 int* __restrict__ cnt) {
  __shared__ float rs[256], rs2[256];
  int row = blockIdx.x, tid = threadIdx.x;
  if (tid == 0) cnt[row] = 0;
  float c[4];
  float s = 0.0f, s2 = 0.0f;
  for (int i = 0; i < 4; ++i) {
    int col = tid + i * 256;
    float v = x[(size_t)row * 1024 + col] + dec[(size_t)row * 1024 + col];
    c[i] = v; s += v; s2 += v * v;
  }
  rs[tid] = s; rs2[tid] = s2;
  __syncthreads();
  for (int st = 128; st > 0; st >>= 1) {
    if (tid < st) { rs[tid] += rs[tid + st]; rs2[tid] += rs2[tid + st]; }
    __syncthreads();
  }
  float mu = rs[0] * (1.0f / 1024.0f);
  float var = rs2[0] * (1.0f / 1024.0f) - mu * mu;
  float inv = rsqrtf(var + 1e-5f);
  for (int i = 0; i < 4; ++i) {
    int col = tid + i * 256;
    out[(size_t)row * 1024 + col] = (c[i] - mu) * inv * gw[col] + bw[col];
  }
}

// ---------------- per-batch top-k via bitonic sort (val desc, idx asc) ----------------
__global__ __launch_bounds__(512) void topk_kernel(const float* __restrict__ imp,
                                                   int* __restrict__ tidx) {
  __shared__ float v[1024];
  __shared__ int ix[1024];
  int b = blockIdx.x, tid = threadIdx.x;
  for (int i = tid; i < 1024; i += 512) { v[i] = imp[b * 1024 + i]; ix[i] = i; }
  __syncthreads();
  for (int k = 2; k <= 1024; k <<= 1) {
    for (int j = k >> 1; j > 0; j >>= 1) {
      for (int t = tid; t < 1024; t += 512) {
        int p = t ^ j;
        if (p > t) {
          float va = v[t], vb = v[p];
          int ia = ix[t], ib = ix[p];
          bool ord = (va > vb) || (va == vb && ia < ib);
          bool up = ((t & k) == 0);
          if (up ? !ord : ord) { v[t] = vb; v[p] = va; ix[t] = ib; ix[p] = ia; }
        }
      }
      __syncthreads();
    }
  }
  for (int t = tid; t < TOPK; t += 512) tidx[b * TOPK + t] = ix[t];
}

// ---------------- EMA update, pass 1: per-row ordered update lists ----------------
__global__ __launch_bounds__(128) void rank_kernel(const int* __restrict__ midx,
                                                   int* __restrict__ cnt,
                                                   int* __restrict__ slot) {
  __shared__ int mi[NUPD];
  int tid = threadIdx.x;
  for (int i = tid; i < NUPD; i += 128) mi[i] = midx[i];
  __syncthreads();
  int j = blockIdx.x * 128 + tid;
  if (j < NUPD) {
    int r = mi[j], rank = 0;
    for (int jp = 0; jp < j; ++jp) rank += (mi[jp] == r) ? 1 : 0;
    if (rank < MAXC) slot[r * MAXC + rank] = j;
    atomicAdd(&cnt[r], 1);
  }
}

// ---------------- EMA update, pass 2: apply (one block per memory row) ----------------
__global__ __launch_bounds__(256) void apply_kernel(const float* __restrict__ x,
                                                    const float* __restrict__ mem,
                                                    const int* __restrict__ tidx,
                                                    const int* __restrict__ cnt,
                                                    const int* __restrict__ slot,
                                                    float* __restrict__ outm) {
  int row = blockIdx.x, tid = threadIdx.x;
  f4 acc = ((const f4*)(mem + (size_t)row * 1024))[tid];
  int c = cnt[row];
  c = c < MAXC ? c : MAXC;
  for (int t = 0; t < c; ++t) {
    int j = slot[row * MAXC + t];
    int b = j / TOPK;
    int tr = tidx[j];
    f4 xv = ((const f4*)(x + ((size_t)b * 1024 + tr) * 1024))[tid];
    acc = acc * 0.99f + xv * 0.01f;
  }
  ((f4*)(outm + (size_t)row * 1024))[tid] = acc;
}

// ---------------- host ----------------
extern "C" void kernel_launch(void* const* d_in, const int* in_sizes, int n_in,
                              void* d_out, int out_size, void* d_ws, size_t ws_size,
                              hipStream_t stream) {
  const float* x = (const float*)d_in[0];
  const float* memory_bank = (const float*)d_in[1];
  const int* memory_indices = (const int*)d_in[2];
  const float* enc_w1 = (const float*)d_in[3];
  const float* enc_b1 = (const float*)d_in[4];
  const float* enc_w2 = (const float*)d_in[5];
  const float* enc_b2 = (const float*)d_in[6];
  const float* wq = (const float*)d_in[7];
  const float* bq = (const float*)d_in[8];
  const float* wk = (const float*)d_in[9];
  const float* bk = (const float*)d_in[10];
  const float* wv = (const float*)d_in[11];
  const float* bv = (const float*)d_in[12];
  const float* wo = (const float*)d_in[13];
  const float* bo = (const float*)d_in[14];
  const float* dec_w1 = (const float*)d_in[15];
  const float* dec_b1 = (const float*)d_in[16];
  const float* dec_w2 = (const float*)d_in[17];
  const float* dec_b2 = (const float*)d_in[18];
  const float* ln_g = (const float*)d_in[19];
  const float* ln_b = (const float*)d_in[20];
  const float* imp_w1 = (const float*)d_in[21];
  const float* imp_b1 = (const float*)d_in[22];
  const float* imp_w2 = (const float*)d_in[23];
  const float* imp_b2 = (const float*)d_in[24];

  // Workspace map (high-water ~72.25MB, within R1-R15 proven range)
  char* ws = (char*)d_ws;
  u16* buf0 = (u16*)(ws);
  u16* buf1 = (u16*)(ws + (8ull << 20));
  u16* buf2 = (u16*)(ws + (16ull << 20));
  u16* buf3 = (u16*)(ws + (24ull << 20));
  u16* buf4 = (u16*)(ws + (32ull << 20));
  float* decb = (float*)(ws + (40ull << 20));
  u16* wtb = (u16*)(ws + (56ull << 20));
  float* impb = (float*)(ws + (72ull << 20));
  int* tidx = (int*)(ws + (72ull << 20) + (1 << 16));
  float* bqp = (float*)(ws + (72ull << 20) + (1 << 17));          // 4KB
  float* bodp = (float*)(ws + (72ull << 20) + (1 << 17) + 4096);  // 4KB
  float* pbuf = (float*)(ws + (72ull << 20) + 196608);            // 64KB bias partials
  int* cnt = (int*)buf3;
  int* slot = (int*)(ws + (24ull << 20) + (1 << 16));
  // prep scratch (dead before attn partials land here)
  u16* w2n = (u16*)(ws + (40ull << 20));  // enc_w2 bf16 row-major, 2MB
  u16* won = (u16*)(ws + (42ull << 20));  // wo bf16 row-major, 2MB
  // attention split-K partials: 4 x 8MB in regions dead at attn time (R10-12-proven)
  u16* cp0 = buf1;
  u16* cp1 = buf2;
  u16* cp2 = (u16*)(ws + (40ull << 20));
  u16* cp3 = (u16*)(ws + (48ull << 20));
  float* ml = (float*)(ws + (56ull << 20));  // wt_e1 region (2MB), dead after mega; 1MB used

  const int NM = 1024 * 1024;
  u16* wt_e1 = wtb + 0 * NM;
  u16* wt_e2q = wtb + 1 * NM;  // (W2*Wq)^T, overwrites wt_e2
  u16* wt_q = wtb + 2 * NM;
  u16* wt_k = wtb + 3 * NM;    // wk^T ; wv^T contiguous for merged KV GEMM
  u16* wt_od = wtb + 5 * NM;   // (Wo*Wd1)^T, overwrites wt_o
  u16* wt_d1 = wtb + 6 * NM;
  u16* wt_d2 = wtb + 7 * NM;

  // activation conversions (paired) + weight transposes
  conv2_kernel<<<8192, 256, 0, stream>>>(x, buf0, memory_bank, buf2, 4096);
  wtrans8_kernel<<<dim3(32, 32, 8), 256, 0, stream>>>(enc_w1, enc_w2, wq, wk, wv, wo,
                                                      dec_w1, dec_w2, wtb);
  conv2_kernel<<<2048, 256, 0, stream>>>(enc_w2, w2n, wo, won, 1024);

  // MEGA: kv + e1 + weight-products + bias partials + importance, one dispatch
  mega_kernel<<<2368, 256, 0, stream>>>(buf2, wt_k, bk, bv, buf3, buf4,        // kv
                                        buf0, wt_e1, enc_b1, buf1,            // e1
                                        wt_q, w2n, wt_e2q, wt_d1, won, wt_od, // sq
                                        enc_b2, wq, bo, dec_w1, pbuf,         // biasA
                                        x, imp_w1, imp_b1, imp_w2, imp_b2, impb);  // imp
  bias_partB<<<8, 256, 0, stream>>>(pbuf, bq, dec_b1, bqp, bodp);

  // q = (gelu1 @ (W2*Wq) + bqp) * QSCALE  (exp2-domain)
  gemm_bt<4><<<512, 256, 0, stream>>>(buf1, wt_e2q, bqp, buf0);

  // attention: 4-way split-K, dual-Q fragments, XCD-pinned heads (2 blocks/CU)
  attn_kernel<2><<<512, 512, 0, stream>>>(buf0, buf3, buf4, cp0, cp1, cp2, cp3, ml);
  combine4_kernel<<<2048, 256, 0, stream>>>(cp0, cp1, cp2, cp3, ml, buf0);

  // fused o+d1 (GELU) -> d2 (f32)
  gemm_bt<1><<<512, 256, 0, stream>>>(buf0, wt_od, bodp, buf1);
  gemm_bt<2><<<512, 256, 0, stream>>>(buf1, wt_d2, dec_b2, decb);
  ln_kernel<<<4096, 256, 0, stream>>>(x, decb, ln_g, ln_b, (float*)d_out, cnt);

  topk_kernel<<<NBATCH, 512, 0, stream>>>(impb, tidx);
  rank_kernel<<<13, 128, 0, stream>>>(memory_indices, cnt, slot);
  apply_kernel<<<4096, 256, 0, stream>>>(x, memory_bank, tidx, cnt, slot,
                                         (float*)d_out + (size_t)ROWS * D_MODEL);
}

// Round 17
// 374.722 us; speedup vs baseline: 1.0191x; 1.0191x over previous
//
#include <hip/hip_runtime.h>

typedef unsigned short u16;
typedef __attribute__((ext_vector_type(4))) int i4;
typedef __attribute__((ext_vector_type(4))) unsigned u4;
typedef __attribute__((ext_vector_type(4))) unsigned short us4;
typedef __attribute__((ext_vector_type(8))) short short8;
typedef __attribute__((ext_vector_type(4))) float f4;

#define D_MODEL 1024
#define ROWS 4096      // B*L and MEM_SIZE
#define NHEAD 8
#define DH 128
#define TOPK 409
#define NUPD 1636      // B*TOPK
#define NBATCH 4
#define MAXC 64        // max chained updates tracked per memory row
#define ATTNROWS 32768 // B*H*L rows of (head-sliced) attention output
// 1/sqrt(128) * log2(e): q pre-scaled so attention softmax works in exp2 domain
#define QSCALE 0.1275174038f

__device__ __forceinline__ u16 f2bf(float f) {
  unsigned u = __builtin_bit_cast(unsigned, f);
  u += 0x7fffu + ((u >> 16) & 1u);
  return (u16)(u >> 16);
}
__device__ __forceinline__ float bf2f(u16 b) {
  unsigned u = ((unsigned)b) << 16;
  return __builtin_bit_cast(float, u);
}
__device__ __forceinline__ float ex2(float x) {  // native v_exp_f32 (2^x)
  return __builtin_amdgcn_exp2f(x);
}
__device__ __forceinline__ float gelu_f(float v) {
  return 0.5f * v * (1.0f + erff(v * 0.70710678118654752f));
}
__device__ __forceinline__ void gload16(const void* g, void* l) {
  __builtin_amdgcn_global_load_lds((const __attribute__((address_space(1))) void*)g,
                                   (__attribute__((address_space(3))) void*)l, 16, 0, 0);
}

// ---------------- paired convert f32 -> bf16 (vectorized) ----------------
__global__ __launch_bounds__(256) void conv2_kernel(const float* __restrict__ in0,
                                                    u16* __restrict__ out0,
                                                    const float* __restrict__ in1,
                                                    u16* __restrict__ out1, int nb) {
  int bid = blockIdx.x;
  const float* in = (bid < nb) ? in0 : in1;
  u16* out = (bid < nb) ? out0 : out1;
  int i = (bid < nb ? bid : bid - nb) * 256 + threadIdx.x;
  f4 v = ((const f4*)in)[i];
  us4 o;
  o.x = f2bf(v.x); o.y = f2bf(v.y); o.z = f2bf(v.z); o.w = f2bf(v.w);
  ((us4*)out)[i] = o;
}

// ---------------- fused weight transpose: 8x w[1024][1024] f32 -> wt[N][K] bf16 ----------------
__global__ __launch_bounds__(256) void wtrans8_kernel(const float* s0, const float* s1,
                                                      const float* s2, const float* s3,
                                                      const float* s4, const float* s5,
                                                      const float* s6, const float* s7,
                                                      u16* __restrict__ dst) {
  const float* srcs[8] = {s0, s1, s2, s3, s4, s5, s6, s7};
  const float* w = srcs[blockIdx.z];
  u16* wt = dst + (size_t)blockIdx.z * (1024 * 1024);
  __shared__ float t[32][33];
  int tx = threadIdx.x & 31, ty = threadIdx.x >> 5;
  int k0 = blockIdx.y * 32, n0 = blockIdx.x * 32;
  for (int r = 0; r < 4; ++r)
    t[ty + r * 8][tx] = w[(size_t)(k0 + ty + r * 8) * 1024 + n0 + tx];
  __syncthreads();
  for (int r = 0; r < 4; ++r)
    wt[(size_t)(n0 + ty + r * 8) * 1024 + k0 + tx] = f2bf(t[tx][ty + r * 8]);
}

// ---------------- bias prep, stage B: reduce + add base bias ----------------
__global__ __launch_bounds__(256) void bias_partB(const float* __restrict__ pbuf,
                                                  const float* __restrict__ bq,
                                                  const float* __restrict__ db1,
                                                  float* __restrict__ bqp,
                                                  float* __restrict__ bodp) {
  int id = blockIdx.x;  // 8 = which*4 + nc
  int which = id >> 2;
  int n = (id & 3) * 256 + threadIdx.x;
  float s = 0.0f;
  for (int kb = 0; kb < 8; ++kb) s += pbuf[(size_t)(which * 8 + kb) * 1024 + n];
  float* out = which ? bodp : bqp;
  const float* badd = which ? db1 : bq;
  out[n] = s + badd[n];
}

// ---------------- shared GEMM core: acc[4][2] += A[m0:m0+128] x BT[n0:n0+64]^T ----------
__device__ __forceinline__ void gemm_core(const u16* __restrict__ A,
                                          const u16* __restrict__ BT,
                                          char* al, char* bl, int m0, int n0,
                                          f4 acc[4][2]) {
  const int K = 1024;
  const int tid = threadIdx.x;
  const int lane = tid & 63;
  const int g = lane >> 4, qi = lane & 15;
  const int wid = tid >> 6;
  const int wr = wid >> 1, wc = wid & 1;
  const int a0r = tid >> 2, a0b = (tid & 3) ^ ((a0r >> 1) & 3);
  const int c1 = tid + 256;
  const int a1r = c1 >> 2, a1b = (c1 & 3) ^ ((a1r >> 1) & 3);
  const int b0r = tid >> 2, b0b = (tid & 3) ^ ((b0r >> 1) & 3);

#define STAGE(buf, kt)                                                                   \
  {                                                                                      \
    const int k0_ = (kt) * 32;                                                           \
    gload16(A + (size_t)(m0 + a0r) * K + k0_ + a0b * 8, al + (buf) * 8192 + tid * 16);   \
    gload16(A + (size_t)(m0 + a1r) * K + k0_ + a1b * 8, al + (buf) * 8192 + c1 * 16);    \
    gload16(BT + (size_t)(n0 + b0r) * K + k0_ + b0b * 8, bl + (buf) * 4096 + tid * 16);  \
  }

  STAGE(0, 0);
  __syncthreads();
  int cur = 0;
  for (int kt = 0; kt < 32; ++kt) {
    if (kt + 1 < 32) STAGE(cur ^ 1, kt + 1);
    short8 af[4], bfr[2];
    for (int i = 0; i < 4; ++i) {
      int r = wr * 64 + i * 16 + qi;
      af[i] = *(const short8*)(al + cur * 8192 + r * 64 + ((g ^ ((r >> 1) & 3))) * 16);
    }
    for (int sn = 0; sn < 2; ++sn) {
      int r = wc * 32 + sn * 16 + qi;
      bfr[sn] = *(const short8*)(bl + cur * 4096 + r * 64 + ((g ^ ((r >> 1) & 3))) * 16);
    }
    for (int i = 0; i < 4; ++i)
      for (int sn = 0; sn < 2; ++sn)
        acc[i][sn] = __builtin_amdgcn_mfma_f32_16x16x32_bf16(af[i], bfr[sn], acc[i][sn], 0, 0, 0);
    __syncthreads();
    cur ^= 1;
  }
#undef STAGE
}

// ---------------- MEGA dispatch: kv(1024) | e1(512) | sq(256) | biasA(64) | imp(512) ----
__global__ __launch_bounds__(256) void mega_kernel(
    const u16* __restrict__ Akv, const u16* __restrict__ BTkv,
    const float* __restrict__ bk, const float* __restrict__ bv,
    u16* __restrict__ Ck, u16* __restrict__ CvT,
    const u16* __restrict__ Ae, const u16* __restrict__ BTe,
    const float* __restrict__ be, u16* __restrict__ Ce,
    const u16* __restrict__ A0, const u16* __restrict__ B0, u16* __restrict__ C0,
    const u16* __restrict__ A1, const u16* __restrict__ B1, u16* __restrict__ C1,
    const float* __restrict__ b2, const float* __restrict__ wqf,
    const float* __restrict__ bo, const float* __restrict__ dw1,
    float* __restrict__ pbuf,
    const float* __restrict__ x, const float* __restrict__ iw1,
    const float* __restrict__ ib1, const float* __restrict__ iw2,
    const float* __restrict__ ib2, float* __restrict__ imp) {
  __shared__ __align__(16) char pool[32768];
  char* al = pool;
  char* bl = pool + 2 * 128 * 64;
  const int gid = blockIdx.x;
  const int tid = threadIdx.x;
  const int lane = tid & 63, wid = tid >> 6;
  const int g = lane >> 4, qi = lane & 15;
  const int wr = wid >> 1, wc = wid & 1;

  if (gid < 1024) {  // ---- merged K/V projection (XCD-pinned) ----
    const int xcd = gid & 7, j = gid >> 3;
    const int m0 = ((j & 3) * 8 + xcd) * 128;
    const int n0 = (j >> 2) * 64;  // 0..2047
    f4 acc[4][2] = {};
    gemm_core(Akv, BTkv, al, bl, m0, n0, acc);
    if (n0 < 1024) {  // K path
      for (int i = 0; i < 4; ++i) {
        int row = m0 + wr * 64 + i * 16 + g * 4;
        for (int sn = 0; sn < 2; ++sn) {
          int col = n0 + wc * 32 + sn * 16 + qi;
          float bvv = bk[col];
          for (int jj = 0; jj < 4; ++jj)
            Ck[(size_t)(row + jj) * 1024 + col] = f2bf(acc[i][sn][jj] + bvv);
        }
      }
    } else {  // V path: transposed store via padded LDS
      u16(*t)[132] = (u16(*)[132])pool;
      __syncthreads();
      for (int i = 0; i < 4; ++i)
        for (int sn = 0; sn < 2; ++sn) {
          int nl = wc * 32 + sn * 16 + qi;
          float bvv = bv[n0 - 1024 + nl];
          for (int jj = 0; jj < 4; ++jj)
            t[nl][wr * 64 + i * 16 + g * 4 + jj] = f2bf(acc[i][sn][jj] + bvv);
        }
      __syncthreads();
      int r = tid >> 2, cg = tid & 3;
      for (int v = 0; v < 4; ++v) {
        us4 val = *(const us4*)&t[r][cg * 32 + v * 8];
        *(us4*)&CvT[(size_t)(n0 - 1024 + r) * 4096 + m0 + cg * 32 + v * 8] = val;
      }
    }
  } else if (gid < 1536) {  // ---- encoder-1 GEMM + GELU (XCD-pinned) ----
    const int id = gid - 1024;
    const int xcd = id & 7, j = id >> 3;
    const int m0 = ((j & 3) * 8 + xcd) * 128;
    const int n0 = (j >> 2) * 64;
    f4 acc[4][2] = {};
    gemm_core(Ae, BTe, al, bl, m0, n0, acc);
    for (int i = 0; i < 4; ++i) {
      int row = m0 + wr * 64 + i * 16 + g * 4;
      for (int sn = 0; sn < 2; ++sn) {
        int col = n0 + wc * 32 + sn * 16 + qi;
        float bv = be[col];
        for (int jj = 0; jj < 4; ++jj)
          Ce[(size_t)(row + jj) * 1024 + col] = f2bf(gelu_f(acc[i][sn][jj] + bv));
      }
    }
  } else if (gid < 1792) {  // ---- dual weight-product GEMM (no bias) ----
    const int id = gid - 1536;
    const int which = id >> 7, j = id & 127;
    const u16* A = which ? A1 : A0;
    const u16* BT = which ? B1 : B0;
    u16* C = which ? C1 : C0;
    const int m0 = (j >> 4) * 128, n0 = (j & 15) * 64;
    f4 acc[4][2] = {};
    gemm_core(A, BT, al, bl, m0, n0, acc);
    for (int i = 0; i < 4; ++i) {
      int row = m0 + wr * 64 + i * 16 + g * 4;
      for (int sn = 0; sn < 2; ++sn) {
        int col = n0 + wc * 32 + sn * 16 + qi;
        for (int jj = 0; jj < 4; ++jj)
          C[(size_t)(row + jj) * 1024 + col] = f2bf(acc[i][sn][jj]);
      }
    }
  } else if (gid < 1856) {  // ---- bias partials ----
    const int lid = gid - 1792;
    const int which = lid >> 5;
    const int kb = (lid >> 2) & 7;
    const int n = (lid & 3) * 256 + tid;
    const float* bvec = which ? bo : b2;
    const float* W = which ? dw1 : wqf;
    float s = 0.0f;
    for (int k = kb * 128; k < kb * 128 + 128; ++k) s += bvec[k] * W[(size_t)k * 1024 + n];
    pbuf[(size_t)(which * 8 + kb) * 1024 + n] = s;
  } else {  // ---- importance scorer (8 rows/block, wave-shuffle reduce) ----
    const int lid = gid - 1856;
    float* xs = (float*)pool;  // [8][1024]
    size_t base = (size_t)lid * 8192;
    for (int i = 0; i < 32; ++i) xs[tid + i * 256] = x[base + tid + i * 256];
    __syncthreads();
    int r0 = wid * 2, r1 = wid * 2 + 1;
    float a0 = 0.0f, a1 = 0.0f;
    for (int k = 0; k < 1024; ++k) {
      float wv = iw1[k * 64 + lane];
      a0 += xs[r0 * 1024 + k] * wv;
      a1 += xs[r1 * 1024 + k] * wv;
    }
    float h0 = gelu_f(a0 + ib1[lane]) * iw2[lane];
    float h1 = gelu_f(a1 + ib1[lane]) * iw2[lane];
    for (int d = 1; d < 64; d <<= 1) {
      h0 += __shfl_xor(h0, d, 64);
      h1 += __shfl_xor(h1, d, 64);
    }
    if (lane == 0) {
      imp[lid * 8 + r0] = 1.0f / (1.0f + expf(-(h0 + ib2[0])));
      imp[lid * 8 + r1] = 1.0f / (1.0f + expf(-(h1 + ib2[0])));
    }
  }
}

// ---------------- bf16 GEMM: C[4096][1024] = A * BT^T + bias ----------------
// EPI: 0 = bf16, 1 = GELU+bf16, 2 = f32, 4 = bf16 * QSCALE (exp2-domain q)
template <int EPI>
__global__ __launch_bounds__(256) void gemm_bt(const u16* __restrict__ A,
                                               const u16* __restrict__ BT,
                                               const float* __restrict__ bias,
                                               void* __restrict__ C) {
  __shared__ __align__(16) char al[2 * 128 * 64];
  __shared__ __align__(16) char bl[2 * 64 * 64];
  const int N = 1024;
  const int id = blockIdx.x;
  const int xcd = id & 7, j = id >> 3;
  const int m0 = ((j & 3) * 8 + xcd) * 128;
  const int n0 = (j >> 2) * 64;
  const int tid = threadIdx.x;
  const int lane = tid & 63, wid = tid >> 6;
  const int g = lane >> 4, qi = lane & 15;
  const int wr = wid >> 1, wc = wid & 1;
  f4 acc[4][2] = {};
  gemm_core(A, BT, al, bl, m0, n0, acc);
  for (int i = 0; i < 4; ++i) {
    int row = m0 + wr * 64 + i * 16 + g * 4;
    for (int sn = 0; sn < 2; ++sn) {
      int col = n0 + wc * 32 + sn * 16 + qi;
      float bv = bias[col];
      for (int jj = 0; jj < 4; ++jj) {
        float v = acc[i][sn][jj] + bv;
        if constexpr (EPI == 1) v = gelu_f(v);
        if constexpr (EPI == 4) v = v * QSCALE;
        if constexpr (EPI == 2)
          ((float*)C)[(size_t)(row + jj) * N + col] = v;
        else
          ((u16*)C)[(size_t)(row + jj) * N + col] = f2bf(v);
      }
    }
  }
}

// ---------------- flash cross-attention, 2-way split-K, dual-Q fragments ----------------
// 8 waves x 32 q-rows each (two 16-q halves share every K/V LDS fragment read -> half the
// DS-read volume per q-row). No min-occupancy bound: compiler allocates VGPR freely.
// Grid 256 = 1 block/CU, h = id&7.
template <int LP>
__global__ __launch_bounds__(512) void attn_kernel(const u16* __restrict__ q,
                                                   const u16* __restrict__ kp,
                                                   const u16* __restrict__ vT,
                                                   u16* __restrict__ cp0, u16* __restrict__ cp1,
                                                   float* __restrict__ ml) {
  constexpr int MR = 4096 >> LP;  // memory rows per part
  constexpr int NT = MR / 64;
  __shared__ __align__(16) char kl[64 * 256];   // K tile [64][128] bf16, XOR-swizzled
  __shared__ __align__(16) char vl[128 * 128];  // V^T tile [128][64] bf16, XOR-swizzled
  const int id = blockIdx.x;
  const int h = id & 7;
  const int rest = id >> 3;
  const int part = rest & ((1 << LP) - 1);
  const int qsec = (rest >> LP) & 3;
  const int b = rest >> (2 + LP);
  const int tid = threadIdx.x;
  const int lane = tid & 63, wid = tid >> 6;
  const int g = lane >> 4, qi = lane & 15;
  const int qrow0 = b * 1024 + qsec * 256 + wid * 32 + qi;  // half 0
  const int qrow1 = qrow0 + 16;                             // half 1
  u16* ctp = (part == 0) ? cp0 : cp1;

  short8 qf0[4], qf1[4];
  for (int kk = 0; kk < 4; ++kk) {
    qf0[kk] = *(const short8*)(q + (size_t)qrow0 * 1024 + h * 128 + kk * 32 + g * 8);
    qf1[kk] = *(const short8*)(q + (size_t)qrow1 * 1024 + h * 128 + kk * 32 + g * 8);
  }

  // staging geometry (2 K-blocks + 2 V-blocks per thread, 512 threads)
  const int kc1 = tid + 512;
  const int kr0 = tid >> 4, kb0 = tid & 15, kr1 = kc1 >> 4, kb1 = kc1 & 15;
  const int vr0 = tid >> 3, vb0 = tid & 7, vr1 = kc1 >> 3, vb1 = kc1 & 7;
  const int kd0 = kr0 * 256 + (kb0 ^ (kr0 & 7)) * 16;
  const int kd1 = kr1 * 256 + (kb1 ^ (kr1 & 7)) * 16;
  const int vd0 = vr0 * 128 + (vb0 ^ (vr0 & 7)) * 16;
  const int vd1 = vr1 * 128 + (vb1 ^ (vr1 & 7)) * 16;
  const int mbase = part * MR;
  const u16* kg0 = kp + (size_t)(mbase + kr0) * 1024 + h * 128 + kb0 * 8;
  const u16* kg1 = kp + (size_t)(mbase + kr1) * 1024 + h * 128 + kb1 * 8;
  const u16* vg0 = vT + (size_t)(h * 128 + vr0) * 4096 + mbase + vb0 * 8;
  const u16* vg1 = vT + (size_t)(h * 128 + vr1) * 4096 + mbase + vb1 * 8;

  i4 kreg0, kreg1, vreg0, vreg1;
#define LOADREGS()                              \
  {                                             \
    kreg0 = *(const i4*)kg0; kg0 += 64 * 1024;  \
    kreg1 = *(const i4*)kg1; kg1 += 64 * 1024;  \
    vreg0 = *(const i4*)vg0; vg0 += 64;         \
    vreg1 = *(const i4*)vg1; vg1 += 64;         \
  }

  f4 ct0[8] = {}, ct1[8] = {};
  float mrun0 = -1e30f, lsum0 = 0.0f, mrun1 = -1e30f, lsum1 = 0.0f;

  LOADREGS();
  for (int mt = 0; mt < NT; ++mt) {
    __syncthreads();
    *(i4*)(kl + kd0) = kreg0; *(i4*)(kl + kd1) = kreg1;
    *(i4*)(vl + vd0) = vreg0; *(i4*)(vl + vd1) = vreg1;
    __syncthreads();
    if (mt + 1 < NT) LOADREGS();  // in flight during compute

    // S^T = K_tile x Q^T for both q-halves; each K fragment feeds 2 MFMAs
    f4 st0[4] = {}, st1[4] = {};
    for (int s = 0; s < 4; ++s) {
      int n = s * 16 + qi;
      const char* krow = kl + n * 256;
      int sw = n & 7;
      for (int kk = 0; kk < 4; ++kk) {
        short8 a = *(const short8*)(krow + ((kk * 4 + g) ^ sw) * 16);
        st0[s] = __builtin_amdgcn_mfma_f32_16x16x32_bf16(a, qf0[kk], st0[s], 0, 0, 0);
        st1[s] = __builtin_amdgcn_mfma_f32_16x16x32_bf16(a, qf1[kk], st1[s], 0, 0, 0);
      }
    }

    short8 pfa0, pfb0, pfa1, pfb1;  // PV B-fragments for halves 0/1, n-chunks a/b
#define SOFTMAX_PACK(ST, MRUN, LSUM, CT, PFA, PFB)                                        \
    {                                                                                     \
      float sv[16];                                                                       \
      float tm = -1e30f;                                                                  \
      for (int s = 0; s < 4; ++s)                                                         \
        for (int jj = 0; jj < 4; ++jj) {                                                  \
          sv[s * 4 + jj] = ST[s][jj];                                                     \
          tm = fmaxf(tm, ST[s][jj]);                                                      \
        }                                                                                 \
      tm = fmaxf(tm, __shfl_xor(tm, 16, 64));                                             \
      tm = fmaxf(tm, __shfl_xor(tm, 32, 64));                                             \
      if (!__all(tm <= MRUN + 8.0f)) {                                                    \
        float mnew = fmaxf(MRUN, tm);                                                     \
        float r = ex2(MRUN - mnew);                                                       \
        LSUM *= r;                                                                        \
        for (int i = 0; i < 8; ++i) CT[i] = CT[i] * r;                                    \
        MRUN = mnew;                                                                      \
      }                                                                                   \
      float psum = 0.0f;                                                                  \
      for (int i = 0; i < 16; ++i) {                                                      \
        float p = ex2(sv[i] - MRUN);                                                      \
        sv[i] = p;                                                                        \
        psum += p;                                                                        \
      }                                                                                   \
      psum += __shfl_xor(psum, 16, 64);                                                   \
      psum += __shfl_xor(psum, 32, 64);                                                   \
      LSUM += psum;                                                                       \
      unsigned pk0[4], pk1[4];                                                            \
      for (int s = 0; s < 4; ++s) {                                                       \
        pk0[s] = (unsigned)f2bf(sv[s * 4 + 0]) | ((unsigned)f2bf(sv[s * 4 + 1]) << 16);   \
        pk1[s] = (unsigned)f2bf(sv[s * 4 + 2]) | ((unsigned)f2bf(sv[s * 4 + 3]) << 16);   \
      }                                                                                   \
      const int src1 = qi + ((g & 1) << 5);                                               \
      const int src2 = src1 + 16;                                                         \
      const bool hi = (g & 2) != 0;                                                       \
      {                                                                                   \
        unsigned a0 = __shfl(pk0[0], src1, 64), b0 = __shfl(pk0[1], src1, 64);            \
        unsigned a1 = __shfl(pk1[0], src1, 64), b1 = __shfl(pk1[1], src1, 64);            \
        unsigned a2 = __shfl(pk0[0], src2, 64), b2 = __shfl(pk0[1], src2, 64);            \
        unsigned a3 = __shfl(pk1[0], src2, 64), b3 = __shfl(pk1[1], src2, 64);            \
        u4 bw;                                                                            \
        bw.x = hi ? b0 : a0; bw.y = hi ? b1 : a1; bw.z = hi ? b2 : a2; bw.w = hi ? b3 : a3;\
        PFA = __builtin_bit_cast(short8, bw);                                             \
      }                                                                                   \
      {                                                                                   \
        unsigned a0 = __shfl(pk0[2], src1, 64), b0 = __shfl(pk0[3], src1, 64);            \
        unsigned a1 = __shfl(pk1[2], src1, 64), b1 = __shfl(pk1[3], src1, 64);            \
        unsigned a2 = __shfl(pk0[2], src2, 64), b2 = __shfl(pk0[3], src2, 64);            \
        unsigned a3 = __shfl(pk1[2], src2, 64), b3 = __shfl(pk1[3], src2, 64);            \
        u4 bw;                                                                            \
        bw.x = hi ? b0 : a0; bw.y = hi ? b1 : a1; bw.z = hi ? b2 : a2; bw.w = hi ? b3 : a3;\
        PFB = __builtin_bit_cast(short8, bw);                                             \
      }                                                                                   \
    }
    SOFTMAX_PACK(st0, mrun0, lsum0, ct0, pfa0, pfb0);
    SOFTMAX_PACK(st1, mrun1, lsum1, ct1, pfa1, pfb1);
#undef SOFTMAX_PACK

    // PV: each V fragment feeds 2 MFMAs (one per q-half)
    for (int d = 0; d < 8; ++d) {
      int dr = d * 16 + qi;
      const char* vrow = vl + dr * 128;
      int swv = dr & 7;
      short8 a0 = *(const short8*)(vrow + ((0 + g) ^ swv) * 16);
      ct0[d] = __builtin_amdgcn_mfma_f32_16x16x32_bf16(a0, pfa0, ct0[d], 0, 0, 0);
      ct1[d] = __builtin_amdgcn_mfma_f32_16x16x32_bf16(a0, pfa1, ct1[d], 0, 0, 0);
      short8 a1 = *(const short8*)(vrow + ((4 + g) ^ swv) * 16);
      ct0[d] = __builtin_amdgcn_mfma_f32_16x16x32_bf16(a1, pfb0, ct0[d], 0, 0, 0);
      ct1[d] = __builtin_amdgcn_mfma_f32_16x16x32_bf16(a1, pfb1, ct1[d], 0, 0, 0);
    }
  }
#undef LOADREGS

  const int obase = ((b * 8 + h) << 10) + qsec * 256 + wid * 32 + qi;
  if (g == 0) {
    ml[(size_t)(part * ATTNROWS + obase) * 2 + 0] = mrun0;
    ml[(size_t)(part * ATTNROWS + obase) * 2 + 1] = lsum0;
    ml[(size_t)(part * ATTNROWS + obase + 16) * 2 + 0] = mrun1;
    ml[(size_t)(part * ATTNROWS + obase + 16) * 2 + 1] = lsum1;
  }
  for (int d = 0; d < 8; ++d) {
    us4 o0, o1;
    o0.x = f2bf(ct0[d][0]); o0.y = f2bf(ct0[d][1]);
    o0.z = f2bf(ct0[d][2]); o0.w = f2bf(ct0[d][3]);
    o1.x = f2bf(ct1[d][0]); o1.y = f2bf(ct1[d][1]);
    o1.z = f2bf(ct1[d][2]); o1.w = f2bf(ct1[d][3]);
    *(us4*)(ctp + (size_t)obase * 128 + d * 16 + g * 4) = o0;
    *(us4*)(ctp + (size_t)(obase + 16) * 128 + d * 16 + g * 4) = o1;
  }
}

// ---------------- combine 2 split-K partials -> ctx [4096][1024] bf16 (exp2 domain) -----
__global__ __launch_bounds__(256) void combine2_kernel(const u16* __restrict__ cp0,
                                                       const u16* __restrict__ cp1,
                                                       const float* __restrict__ ml,
                                                       u16* __restrict__ ctx) {
  int tid = threadIdx.x;
  int row = blockIdx.x * 16 + (tid >> 4);
  int dp = (tid & 15) * 8;
  float m0 = ml[(size_t)row * 2], l0 = ml[(size_t)row * 2 + 1];
  float m1 = ml[((size_t)ATTNROWS + row) * 2], l1 = ml[((size_t)ATTNROWS + row) * 2 + 1];
  float m = fmaxf(m0, m1);
  float s0 = ex2(m0 - m), s1 = ex2(m1 - m);
  float inv = 1.0f / (l0 * s0 + l1 * s1);
  short8 c0 = *(const short8*)(cp0 + (size_t)row * 128 + dp);
  short8 c1 = *(const short8*)(cp1 + (size_t)row * 128 + dp);
  us4 o[2];
  for (int i = 0; i < 8; ++i) {
    float f = (bf2f((u16)c0[i]) * s0 + bf2f((u16)c1[i]) * s1) * inv;
    ((u16*)o)[i] = f2bf(f);
  }
  int bb = row >> 13, hh = (row >> 10) & 7, qr = row & 1023;
  *(short8*)(ctx + (size_t)((bb << 10) + qr) * 1024 + hh * 128 + dp) =
      __builtin_bit_cast(short8, o);
}

// ---------------- residual + LayerNorm (also zeroes EMA cnt) ----------------
__global__ __launch_bounds__(256) void ln_kernel(const float* __restrict__ x,
                                                 const float* __restrict__ dec,
                                                 const float* __restrict__ gw,
                                                 const float* __restrict__ bw,
                                                 float* __restrict__ out,
                                                 int* __restrict__ cnt) {
  __shared__ float rs[256], rs2[256];
  int row = blockIdx.x, tid = threadIdx.x;
  if (tid == 0) cnt[row] = 0;
  float c[4];
  float s = 0.0f, s2 = 0.0f;
  for (int i = 0; i < 4; ++i) {
    int col = tid + i * 256;
    float v = x[(size_t)row * 1024 + col] + dec[(size_t)row * 1024 + col];
    c[i] = v; s += v; s2 += v * v;
  }
  rs[tid] = s; rs2[tid] = s2;
  __syncthreads();
  for (int st = 128; st > 0; st >>= 1) {
    if (tid < st) { rs[tid] += rs[tid + st]; rs2[tid] += rs2[tid + st]; }
    __syncthreads();
  }
  float mu = rs[0] * (1.0f / 1024.0f);
  float var = rs2[0] * (1.0f / 1024.0f) - mu * mu;
  float inv = rsqrtf(var + 1e-5f);
  for (int i = 0; i < 4; ++i) {
    int col = tid + i * 256;
    out[(size_t)row * 1024 + col] = (c[i] - mu) * inv * gw[col] + bw[col];
  }
}

// ---------------- per-batch top-k via bitonic sort (val desc, idx asc) ----------------
__global__ __launch_bounds__(512) void topk_kernel(const float* __restrict__ imp,
                                                   int* __restrict__ tidx) {
  __shared__ float v[1024];
  __shared__ int ix[1024];
  int b = blockIdx.x, tid = threadIdx.x;
  for (int i = tid; i < 1024; i += 512) { v[i] = imp[b * 1024 + i]; ix[i] = i; }
  __syncthreads();
  for (int k = 2; k <= 1024; k <<= 1) {
    for (int j = k >> 1; j > 0; j >>= 1) {
      for (int t = tid; t < 1024; t += 512) {
        int p = t ^ j;
        if (p > t) {
          float va = v[t], vb = v[p];
          int ia = ix[t], ib = ix[p];
          bool ord = (va > vb) || (va == vb && ia < ib);
          bool up = ((t & k) == 0);
          if (up ? !ord : ord) { v[t] = vb; v[p] = va; ix[t] = ib; ix[p] = ia; }
        }
      }
      __syncthreads();
    }
  }
  for (int t = tid; t < TOPK; t += 512) tidx[b * TOPK + t] = ix[t];
}

// ---------------- EMA update, pass 1: per-row ordered update lists ----------------
__global__ __launch_bounds__(128) void rank_kernel(const int* __restrict__ midx,
                                                   int* __restrict__ cnt,
                                                   int* __restrict__ slot) {
  __shared__ int mi[NUPD];
  int tid = threadIdx.x;
  for (int i = tid; i < NUPD; i += 128) mi[i] = midx[i];
  __syncthreads();
  int j = blockIdx.x * 128 + tid;
  if (j < NUPD) {
    int r = mi[j], rank = 0;
    for (int jp = 0; jp < j; ++jp) rank += (mi[jp] == r) ? 1 : 0;
    if (rank < MAXC) slot[r * MAXC + rank] = j;
    atomicAdd(&cnt[r], 1);
  }
}

// ---------------- EMA update, pass 2: apply (one block per memory row) ----------------
__global__ __launch_bounds__(256) void apply_kernel(const float* __restrict__ x,
                                                    const float* __restrict__ mem,
                                                    const int* __restrict__ tidx,
                                                    const int* __restrict__ cnt,
                                                    const int* __restrict__ slot,
                                                    float* __restrict__ outm) {
  int row = blockIdx.x, tid = threadIdx.x;
  f4 acc = ((const f4*)(mem + (size_t)row * 1024))[tid];
  int c = cnt[row];
  c = c < MAXC ? c : MAXC;
  for (int t = 0; t < c; ++t) {
    int j = slot[row * MAXC + t];
    int b = j / TOPK;
    int tr = tidx[j];
    f4 xv = ((const f4*)(x + ((size_t)b * 1024 + tr) * 1024))[tid];
    acc = acc * 0.99f + xv * 0.01f;
  }
  ((f4*)(outm + (size_t)row * 1024))[tid] = acc;
}

// ---------------- host ----------------
extern "C" void kernel_launch(void* const* d_in, const int* in_sizes, int n_in,
                              void* d_out, int out_size, void* d_ws, size_t ws_size,
                              hipStream_t stream) {
  const float* x = (const float*)d_in[0];
  const float* memory_bank = (const float*)d_in[1];
  const int* memory_indices = (const int*)d_in[2];
  const float* enc_w1 = (const float*)d_in[3];
  const float* enc_b1 = (const float*)d_in[4];
  const float* enc_w2 = (const float*)d_in[5];
  const float* enc_b2 = (const float*)d_in[6];
  const float* wq = (const float*)d_in[7];
  const float* bq = (const float*)d_in[8];
  const float* wk = (const float*)d_in[9];
  const float* bk = (const float*)d_in[10];
  const float* wv = (const float*)d_in[11];
  const float* bv = (const float*)d_in[12];
  const float* wo = (const float*)d_in[13];
  const float* bo = (const float*)d_in[14];
  const float* dec_w1 = (const float*)d_in[15];
  const float* dec_b1 = (const float*)d_in[16];
  const float* dec_w2 = (const float*)d_in[17];
  const float* dec_b2 = (const float*)d_in[18];
  const float* ln_g = (const float*)d_in[19];
  const float* ln_b = (const float*)d_in[20];
  const float* imp_w1 = (const float*)d_in[21];
  const float* imp_b1 = (const float*)d_in[22];
  const float* imp_w2 = (const float*)d_in[23];
  const float* imp_b2 = (const float*)d_in[24];

  // Workspace map (high-water ~72.25MB, within R1-R15 proven range)
  char* ws = (char*)d_ws;
  u16* buf0 = (u16*)(ws);
  u16* buf1 = (u16*)(ws + (8ull << 20));
  u16* buf2 = (u16*)(ws + (16ull << 20));
  u16* buf3 = (u16*)(ws + (24ull << 20));
  u16* buf4 = (u16*)(ws + (32ull << 20));
  float* decb = (float*)(ws + (40ull << 20));
  u16* wtb = (u16*)(ws + (56ull << 20));
  float* impb = (float*)(ws + (72ull << 20));
  int* tidx = (int*)(ws + (72ull << 20) + (1 << 16));
  float* bqp = (float*)(ws + (72ull << 20) + (1 << 17));          // 4KB
  float* bodp = (float*)(ws + (72ull << 20) + (1 << 17) + 4096);  // 4KB
  float* pbuf = (float*)(ws + (72ull << 20) + 196608);            // 64KB bias partials
  int* cnt = (int*)buf3;
  int* slot = (int*)(ws + (24ull << 20) + (1 << 16));
  // prep scratch (dead before attn partials land here)
  u16* w2n = (u16*)(ws + (40ull << 20));  // enc_w2 bf16 row-major, 2MB
  u16* won = (u16*)(ws + (42ull << 20));  // wo bf16 row-major, 2MB
  // attention split-K partials: 2 x 8MB in regions dead at attn time
  u16* cp0 = buf1;
  u16* cp1 = buf2;
  float* ml = (float*)(ws + (56ull << 20));  // wt_e1 region, dead after mega

  const int NM = 1024 * 1024;
  u16* wt_e1 = wtb + 0 * NM;
  u16* wt_e2q = wtb + 1 * NM;  // (W2*Wq)^T, overwrites wt_e2
  u16* wt_q = wtb + 2 * NM;
  u16* wt_k = wtb + 3 * NM;    // wk^T ; wv^T contiguous for merged KV GEMM
  u16* wt_od = wtb + 5 * NM;   // (Wo*Wd1)^T, overwrites wt_o
  u16* wt_d1 = wtb + 6 * NM;
  u16* wt_d2 = wtb + 7 * NM;

  // activation conversions (paired) + weight transposes
  conv2_kernel<<<8192, 256, 0, stream>>>(x, buf0, memory_bank, buf2, 4096);
  wtrans8_kernel<<<dim3(32, 32, 8), 256, 0, stream>>>(enc_w1, enc_w2, wq, wk, wv, wo,
                                                      dec_w1, dec_w2, wtb);
  conv2_kernel<<<2048, 256, 0, stream>>>(enc_w2, w2n, wo, won, 1024);

  // MEGA: kv + e1 + weight-products + bias partials + importance, one dispatch
  mega_kernel<<<2368, 256, 0, stream>>>(buf2, wt_k, bk, bv, buf3, buf4,        // kv
                                        buf0, wt_e1, enc_b1, buf1,            // e1
                                        wt_q, w2n, wt_e2q, wt_d1, won, wt_od, // sq
                                        enc_b2, wq, bo, dec_w1, pbuf,         // biasA
                                        x, imp_w1, imp_b1, imp_w2, imp_b2, impb);  // imp
  bias_partB<<<8, 256, 0, stream>>>(pbuf, bq, dec_b1, bqp, bodp);

  // q = (gelu1 @ (W2*Wq) + bqp) * QSCALE  (exp2-domain)
  gemm_bt<4><<<512, 256, 0, stream>>>(buf1, wt_e2q, bqp, buf0);

  // attention: 2-way split-K, dual-Q fragments, XCD-pinned heads
  attn_kernel<1><<<256, 512, 0, stream>>>(buf0, buf3, buf4, cp0, cp1, ml);
  combine2_kernel<<<2048, 256, 0, stream>>>(cp0, cp1, ml, buf0);

  // fused o+d1 (GELU) -> d2 (f32)
  gemm_bt<1><<<512, 256, 0, stream>>>(buf0, wt_od, bodp, buf1);
  gemm_bt<2><<<512, 256, 0, stream>>>(buf1, wt_d2, dec_b2, decb);
  ln_kernel<<<4096, 256, 0, stream>>>(x, decb, ln_g, ln_b, (float*)d_out, cnt);

  topk_kernel<<<NBATCH, 512, 0, stream>>>(impb, tidx);
  rank_kernel<<<13, 128, 0, stream>>>(memory_indices, cnt, slot);
  apply_kernel<<<4096, 256, 0, stream>>>(x, memory_bank, tidx, cnt, slot,
                                         (float*)d_out + (size_t)ROWS * D_MODEL);
}